// Round 1
// baseline (46.304 us; speedup 1.0000x reference)
//
#include <hip/hip_runtime.h>
#include <math.h>

#define EPSF 1e-20f
#define BB 4
#define CC 16
#define HH 256
#define WW 256
#define HP 128
#define KK 4

__device__ __forceinline__ float softplusf(float x) {
    // stable softplus: max(x,0) + log1p(exp(-|x|))
    return fmaxf(x, 0.0f) + log1pf(expf(-fabsf(x)));
}

// Kernel 1: per (b,c,oh,ow) at 128x128:
//   dual argmax over 4x4/stride2/pad1 patches of (d*cd) and (cd/(d+eps)),
//   gather d/cd at both argmax positions, propagation math,
//   write x1 = cs_prop * s_prop, x2 = cs_prop into workspace.
__global__ __launch_bounds__(256) void k1_prop(
    const float* __restrict__ d, const float* __restrict__ cd,
    const float* __restrict__ s, const float* __restrict__ cs,
    const float* __restrict__ w_s_from_d, const float* __restrict__ w_prop,
    float* __restrict__ x1, float* __restrict__ x2)
{
    int t = blockIdx.x * 256 + threadIdx.x;          // 0 .. 4*16*128*128-1
    int ow = t & (HP - 1);
    int oh = (t >> 7) & (HP - 1);
    int bc = t >> 14;                                // 0..63
    const float* dp  = d  + (size_t)bc * HH * WW;
    const float* cdp = cd + (size_t)bc * HH * WW;

    float best1 = -INFINITY, best2 = -INFINITY;
    float d_max = 0.f, cd_max = 0.f, d_min = 0.f, cd_min = 0.f;
    int r0 = oh * 2 - 1;
    int c0 = ow * 2 - 1;

    #pragma unroll
    for (int kh = 0; kh < KK; ++kh) {
        int r = r0 + kh;
        if (r < 0 || r >= HH) continue;
        #pragma unroll
        for (int kw = 0; kw < KK; ++kw) {
            int cidx = c0 + kw;
            if (cidx < 0 || cidx >= WW) continue;
            float dv  = dp[r * WW + cidx];
            float cdv = cdp[r * WW + cidx];
            float v1 = dv * cdv;
            float v2 = cdv / (dv + EPSF);
            if (v1 > best1) { best1 = v1; d_max = dv; cd_max = cdv; }
            if (v2 > best2) { best2 = v2; d_min = dv; cd_min = cdv; }
        }
    }

    float m = fabsf(d_min / (d_max + EPSF));
    float a0 = w_s_from_d[0];
    float a1 = w_s_from_d[1];
    float sfd  = (1.0f - a0 - a1) * m + a0 * m * m + a1 * m * m * m;
    float csfd = cd_max * cd_min;
    float wp   = softplusf(w_prop[0]);

    float sv  = s[t];
    float csv = cs[t];
    float denom_p = wp * csv + csfd;
    float s_prop  = (wp * csv * sv + csfd * sfd) / (denom_p + EPSF);
    float cs_prop = denom_p / (wp + 1.0f);

    x1[t] = cs_prop * s_prop;
    x2[t] = cs_prop;
}

// Kernel 2: transposed depthwise conv (stride 2, K=4, pad 1) + fused epilogue.
// out[i,j] = sum_{u,v valid} x[(i+1-u)/2, (j+1-v)/2] * sw[u,v],
// with u ≡ (i+1) mod 2, u in {u0, u0+2}; cdenom = sum of valid sw taps.
__global__ __launch_bounds__(256) void k2_deconv(
    const float* __restrict__ x1, const float* __restrict__ x2,
    const float* __restrict__ spatial_weight, const float* __restrict__ bias,
    float* __restrict__ s_out, float* __restrict__ cs_out)
{
    __shared__ float sw[16];
    int t = blockIdx.x * 256 + threadIdx.x;          // 0 .. 4*16*256*256-1
    int j = t & (WW - 1);
    int i = (t >> 8) & (HH - 1);
    int bc = t >> 16;                                // block-uniform (one row per block)
    int c = bc & (CC - 1);

    if (threadIdx.x < 16)
        sw[threadIdx.x] = softplusf(spatial_weight[c * 16 + threadIdx.x]);
    __syncthreads();

    const float* x1p = x1 + (size_t)bc * HP * HP;
    const float* x2p = x2 + (size_t)bc * HP * HP;

    int u0 = (i + 1) & 1;
    int v0 = (j + 1) & 1;
    float nom = 0.f, den = 0.f, cden = 0.f;

    #pragma unroll
    for (int du = 0; du < 2; ++du) {
        int u = u0 + 2 * du;
        int mm = (i + 1 - u) >> 1;                   // even difference, arithmetic ok
        if (mm < 0 || mm >= HP) continue;
        #pragma unroll
        for (int dv = 0; dv < 2; ++dv) {
            int v = v0 + 2 * dv;
            int nn = (j + 1 - v) >> 1;
            if (nn < 0 || nn >= HP) continue;
            float swv = sw[u * 4 + v];
            nom  = fmaf(x1p[mm * HP + nn], swv, nom);
            den  = fmaf(x2p[mm * HP + nn], swv, den);
            cden += swv;
        }
    }

    s_out[t]  = nom / (den + EPSF) + bias[c];
    cs_out[t] = den / cden;
}

extern "C" void kernel_launch(void* const* d_in, const int* in_sizes, int n_in,
                              void* d_out, int out_size, void* d_ws, size_t ws_size,
                              hipStream_t stream) {
    const float* d    = (const float*)d_in[0];
    const float* cd   = (const float*)d_in[1];
    const float* s    = (const float*)d_in[2];
    const float* cs   = (const float*)d_in[3];
    const float* wsd  = (const float*)d_in[4];
    const float* wpr  = (const float*)d_in[5];
    const float* spw  = (const float*)d_in[6];
    const float* bias = (const float*)d_in[7];

    float* out    = (float*)d_out;
    float* x1     = (float*)d_ws;                       // 4*16*128*128 floats = 4 MB
    float* x2     = x1 + (size_t)BB * CC * HP * HP;     // another 4 MB
    float* s_out  = out;
    float* cs_out = out + (size_t)BB * CC * HH * WW;

    int n1 = BB * CC * HP * HP;      // 1,048,576
    int n2 = BB * CC * HH * WW;      // 4,194,304

    k1_prop<<<n1 / 256, 256, 0, stream>>>(d, cd, s, cs, wsd, wpr, x1, x2);
    k2_deconv<<<n2 / 256, 256, 0, stream>>>(x1, x2, spw, bias, s_out, cs_out);
}

// Round 2
// 33.885 us; speedup vs baseline: 1.3665x; 1.3665x over previous
//
#include <hip/hip_runtime.h>
#include <math.h>

#define EPSF 1e-20f
#define HH 256
#define WW 256
#define HP 128
#define PW 132              // padded x-buffer width  (1 + 128 + 3)
#define PH 130              // padded x-buffer height (1 + 128 + 1)
#define PPL (PH*PW)         // 17160 floats per (b,c) plane
#define NPL 64              // number of (b,c) planes
#define PAD_PER_PLANE 776   // 2*132 + 128*4 pad cells
#define K1_INT_BLOCKS 2048  // 524288 interior threads (64 g * 128 oh * 64 bc)
#define K1_PAD_BLOCKS 194   // 49664 pad cells
#define NEG_INF (-INFINITY)

__device__ __forceinline__ float softplusf(float x) {
    return fmaxf(x, 0.0f) + log1pf(expf(-fabsf(x)));
}

// K1: each interior thread computes outputs (oh, 2g) and (oh, 2g+1).
// Shared 4-row x 6-col window, branch-free -inf masking (matches the
// reference's -inf padding + first-index argmax tie-break exactly).
// Extra blocks zero the pad cells of the padded x1/x2 buffers.
__global__ __launch_bounds__(256) void k1_prop(
    const float* __restrict__ d, const float* __restrict__ cd,
    const float* __restrict__ s, const float* __restrict__ cs,
    const float* __restrict__ w_s_from_d, const float* __restrict__ w_prop,
    float* __restrict__ x1, float* __restrict__ x2)
{
    int bx = blockIdx.x;
    if (bx >= K1_INT_BLOCKS) {
        int pidx = (bx - K1_INT_BLOCKS) * 256 + threadIdx.x;
        if (pidx < NPL * PAD_PER_PLANE) {
            int plane = pidx / PAD_PER_PLANE;
            int k = pidx - plane * PAD_PER_PLANE;
            int pr, pc;
            if (k < 264) { pr = (k < 132) ? 0 : (PH - 1); pc = (k < 132) ? k : (k - 132); }
            else { int kk = k - 264; pr = 1 + (kk >> 2); int m = kk & 3; pc = (m == 0) ? 0 : (128 + m); }
            int off = plane * PPL + pr * PW + pc;
            x1[off] = 0.f; x2[off] = 0.f;
        }
        return;
    }

    int t  = bx * 256 + threadIdx.x;      // 0 .. 524287
    int g  = t & 63;                      // ow pair index
    int oh = (t >> 6) & 127;
    int bc = t >> 13;                     // 0..63

    const float* dp  = d  + (size_t)bc * HH * WW;
    const float* cdp = cd + (size_t)bc * HH * WW;

    int cb   = 4 * g;                     // aligned float4 base col
    int c_lo = (cb - 1 < 0) ? 0 : cb - 1; // clamped edge cols (masked below)
    int c_hi = (cb + 4 > WW - 1) ? (WW - 1) : (cb + 4);
    int r0   = 2 * oh - 1;

    float bA1 = NEG_INF, dA1 = 0.f, cA1 = 0.f;   // argmax of d*cd, output A
    float bA2 = NEG_INF, dA2 = 0.f, cA2 = 0.f;   // argmax of cd/(d+eps), A
    float bB1 = NEG_INF, dB1 = 0.f, cB1 = 0.f;
    float bB2 = NEG_INF, dB2 = 0.f, cB2 = 0.f;

    #pragma unroll
    for (int kh = 0; kh < 4; ++kh) {
        int r  = r0 + kh;
        int rl = r < 0 ? 0 : (r > HH - 1 ? HH - 1 : r);
        bool rv = (r >= 0) && (r < HH);
        const float* drow = dp  + rl * WW;
        const float* crow = cdp + rl * WW;

        float4 d4 = *(const float4*)(drow + cb);
        float4 c4 = *(const float4*)(crow + cb);
        float wd[6] = { drow[c_lo], d4.x, d4.y, d4.z, d4.w, drow[c_hi] };
        float wc[6] = { crow[c_lo], c4.x, c4.y, c4.z, c4.w, crow[c_hi] };
        bool mv[6];
        mv[0] = rv && (g > 0);
        mv[1] = rv; mv[2] = rv; mv[3] = rv; mv[4] = rv;
        mv[5] = rv && (g < 63);

        #pragma unroll
        for (int idx = 0; idx < 6; ++idx) {
            float v1 = mv[idx] ? wd[idx] * wc[idx]          : NEG_INF;
            float v2 = mv[idx] ? wc[idx] / (wd[idx] + EPSF) : NEG_INF;
            if (idx <= 3) {   // patch A: cols cb-1 .. cb+2
                bool u = v1 > bA1;
                bA1 = u ? v1 : bA1; dA1 = u ? wd[idx] : dA1; cA1 = u ? wc[idx] : cA1;
                bool w = v2 > bA2;
                bA2 = w ? v2 : bA2; dA2 = w ? wd[idx] : dA2; cA2 = w ? wc[idx] : cA2;
            }
            if (idx >= 2) {   // patch B: cols cb+1 .. cb+4
                bool u = v1 > bB1;
                bB1 = u ? v1 : bB1; dB1 = u ? wd[idx] : dB1; cB1 = u ? wc[idx] : cB1;
                bool w = v2 > bB2;
                bB2 = w ? v2 : bB2; dB2 = w ? wd[idx] : dB2; cB2 = w ? wc[idx] : cB2;
            }
        }
    }

    float a0 = w_s_from_d[0];
    float a1 = w_s_from_d[1];
    float wp = softplusf(w_prop[0]);

    int sidx = bc * (HP * HP) + oh * HP + 2 * g;
    float2 sv2  = *(const float2*)(s  + sidx);
    float2 csv2 = *(const float2*)(cs + sidx);

    // output A
    float mA  = fabsf(dA2 / (dA1 + EPSF));
    float sfdA  = (1.0f - a0 - a1) * mA + a0 * mA * mA + a1 * mA * mA * mA;
    float csfdA = cA1 * cA2;
    float denA  = wp * csv2.x + csfdA;
    float spA   = (wp * csv2.x * sv2.x + csfdA * sfdA) / (denA + EPSF);
    float cpA   = denA / (wp + 1.0f);
    // output B
    float mB  = fabsf(dB2 / (dB1 + EPSF));
    float sfdB  = (1.0f - a0 - a1) * mB + a0 * mB * mB + a1 * mB * mB * mB;
    float csfdB = cB1 * cB2;
    float denB  = wp * csv2.y + csfdB;
    float spB   = (wp * csv2.y * sv2.y + csfdB * sfdB) / (denB + EPSF);
    float cpB   = denB / (wp + 1.0f);

    int ob = bc * PPL + (oh + 1) * PW + (1 + 2 * g);
    x1[ob]     = cpA * spA;
    x1[ob + 1] = cpB * spB;
    x2[ob]     = cpA;
    x2[ob + 1] = cpB;
}

// K2: transposed depthwise conv (stride 2, K=4, pad 1) + fused epilogue.
// 8 outputs per thread; zero-padded x buffers make the data path branch-free;
// cden reconstructed from tap validity arithmetically.
__global__ __launch_bounds__(256) void k2_deconv(
    const float* __restrict__ x1, const float* __restrict__ x2,
    const float* __restrict__ spatial_weight, const float* __restrict__ bias,
    float* __restrict__ s_out, float* __restrict__ cs_out)
{
    __shared__ float sw[16];
    int t  = blockIdx.x * 256 + threadIdx.x;   // 0 .. 524287 (2048 blocks)
    int q  = t & 31;                           // j-group: j = 8q .. 8q+7
    int i  = (t >> 5) & 255;
    int bc = t >> 13;                          // block-uniform
    int c  = bc & 15;

    if (threadIdx.x < 16)
        sw[threadIdx.x] = softplusf(spatial_weight[c * 16 + threadIdx.x]);
    __syncthreads();

    int u0  = (i + 1) & 1;
    int m0  = (i + 1 - u0) >> 1;   // 0..128 ; tap rows: mm=m0 (u=u0), mm=m0-1 (u=u0+2)
    int pr0 = m0 + 1;              // padded row of m0   (129 = bottom pad when m0=128)
    int pr1 = m0;                  // padded row of m0-1 (0   = top pad when m0=0)
    float rv0 = (m0 <= 127) ? 1.f : 0.f;
    float rv1 = (m0 >= 1)   ? 1.f : 0.f;

    const float* x1p = x1 + (size_t)bc * PPL;
    const float* x2p = x2 + (size_t)bc * PPL;
    int colb = 4 * q;              // padded col base; reg j <-> nn = 4q + j - 1

    float A0[6], A1[6], B0[6], B1[6];
    {
        const float* p = x1p + pr0 * PW + colb;
        float4 t4 = *(const float4*)p;  float2 t2 = *(const float2*)(p + 4);
        A0[0]=t4.x; A0[1]=t4.y; A0[2]=t4.z; A0[3]=t4.w; A0[4]=t2.x; A0[5]=t2.y;
    }
    {
        const float* p = x1p + pr1 * PW + colb;
        float4 t4 = *(const float4*)p;  float2 t2 = *(const float2*)(p + 4);
        A1[0]=t4.x; A1[1]=t4.y; A1[2]=t4.z; A1[3]=t4.w; A1[4]=t2.x; A1[5]=t2.y;
    }
    {
        const float* p = x2p + pr0 * PW + colb;
        float4 t4 = *(const float4*)p;  float2 t2 = *(const float2*)(p + 4);
        B0[0]=t4.x; B0[1]=t4.y; B0[2]=t4.z; B0[3]=t4.w; B0[4]=t2.x; B0[5]=t2.y;
    }
    {
        const float* p = x2p + pr1 * PW + colb;
        float4 t4 = *(const float4*)p;  float2 t2 = *(const float2*)(p + 4);
        B1[0]=t4.x; B1[1]=t4.y; B1[2]=t4.z; B1[3]=t4.w; B1[4]=t2.x; B1[5]=t2.y;
    }

    // wave-uniform weight broadcasts
    float sa0 = sw[u0*4 + 0], sb0 = sw[u0*4 + 2], sc0 = sw[(u0+2)*4 + 0], sd0 = sw[(u0+2)*4 + 2];
    float sa1 = sw[u0*4 + 1], sb1 = sw[u0*4 + 3], sc1 = sw[(u0+2)*4 + 1], sd1 = sw[(u0+2)*4 + 3];
    float bv = bias[c];

    float so[8], co[8];
    #pragma unroll
    for (int e = 0; e < 8; ++e) {
        const int v0   = (e + 1) & 1;
        const int offH = (e + 1 - v0) >> 1;       // 0,1,1,2,2,3,3,4
        const int iH   = offH + 1;                // reg idx of tap dv=0 (v=v0)
        const int iL   = offH;                    // reg idx of tap dv=1 (v=v0+2)
        float swa = v0 ? sa1 : sa0;   // (u0,   v0)
        float swb = v0 ? sb1 : sb0;   // (u0,   v0+2)
        float swc = v0 ? sc1 : sc0;   // (u0+2, v0)
        float swd = v0 ? sd1 : sd0;   // (u0+2, v0+2)

        float nom = swa*A0[iH] + swb*A0[iL] + swc*A1[iH] + swd*A1[iL];
        float den = swa*B0[iH] + swb*B0[iL] + swc*B1[iH] + swd*B1[iL];

        float cvH = 1.f, cvL = 1.f;
        if (e == 0) cvL = (q >= 1)  ? 1.f : 0.f;   // nn = 4q-1
        if (e == 7) cvH = (q <= 30) ? 1.f : 0.f;   // nn = 4q+4
        float cden = (swa*cvH + swb*cvL) * rv0 + (swc*cvH + swd*cvL) * rv1;

        so[e] = nom / (den + EPSF) + bv;
        co[e] = den / cden;
    }

    int ob = bc * (HH * WW) + i * WW + 8 * q;
    *(float4*)(s_out  + ob    ) = make_float4(so[0], so[1], so[2], so[3]);
    *(float4*)(s_out  + ob + 4) = make_float4(so[4], so[5], so[6], so[7]);
    *(float4*)(cs_out + ob    ) = make_float4(co[0], co[1], co[2], co[3]);
    *(float4*)(cs_out + ob + 4) = make_float4(co[4], co[5], co[6], co[7]);
}

extern "C" void kernel_launch(void* const* d_in, const int* in_sizes, int n_in,
                              void* d_out, int out_size, void* d_ws, size_t ws_size,
                              hipStream_t stream) {
    const float* d    = (const float*)d_in[0];
    const float* cd   = (const float*)d_in[1];
    const float* s    = (const float*)d_in[2];
    const float* cs   = (const float*)d_in[3];
    const float* wsd  = (const float*)d_in[4];
    const float* wpr  = (const float*)d_in[5];
    const float* spw  = (const float*)d_in[6];
    const float* bias = (const float*)d_in[7];

    float* out    = (float*)d_out;
    float* x1     = (float*)d_ws;                 // 64*130*132 floats ≈ 4.4 MB
    float* x2     = x1 + (size_t)NPL * PPL;       // same again
    float* s_o    = out;
    float* cs_o   = out + (size_t)4 * 16 * HH * WW;

    k1_prop<<<K1_INT_BLOCKS + K1_PAD_BLOCKS, 256, 0, stream>>>(d, cd, s, cs, wsd, wpr, x1, x2);
    k2_deconv<<<2048, 256, 0, stream>>>(x1, x2, spw, bias, s_o, cs_o);
}